// Round 6
// baseline (853.768 us; speedup 1.0000x reference)
//
#include <hip/hip_runtime.h>
#include <hip/hip_bf16.h>
#include <stdint.h>

// SparseLinear: out = x @ (W*mask)^T + b == bf16 MFMA GEMM, M=8192 N=4096 K=4096.
// R6 == R5 resubmit (R5 never ran: GPU acquisition timeout; schedule re-audited).
// Fine-grained 4-phase/K-tile pipeline (T3+T4 derived): K-slice=16,
// mfma 32x32x16, stage slice ph of tile t+1 at phase ph of tile t ->
// uniform 4-phase prefetch distance, constant vmcnt(6) gate per phase.
// One barrier per phase. Tail tile drains 6,4,2,0.
// Ledger: slice (t+1,ph) overwrites buf-q slice (t-1,ph), last read at tile
// t-1 phase ph (>=4 phase-barriers earlier). Reads of slice (t,ph) gated by
// per-wave vmcnt(6) BEFORE s_barrier (so after the barrier, every wave's
// staging contribution has landed). All ds_reads are MFMA-consumed before the
// next barrier (compiler lgkmcnt), so no LDS read crosses a barrier.

#define MDIM 8192
#define NDIM 4096
#define KDIM 4096

typedef __bf16   bf16x8 __attribute__((ext_vector_type(8)));
typedef float    f32x16 __attribute__((ext_vector_type(16)));
typedef uint16_t u16x8  __attribute__((ext_vector_type(8)));

__device__ __forceinline__ uint16_t f32_to_bf16_rne(float f) {
  union { float f; uint32_t u; } v; v.f = f;
  uint32_t u = v.u;
  return (uint16_t)((u + 0x7fffu + ((u >> 16) & 1u)) >> 16);
}

// ---- mask dtype detection (uint8 bool vs int32 bool), flag -> d_out[0] ----
__global__ void detect_mask_kernel(const uint32_t* __restrict__ mask,
                                   int* __restrict__ flag) {
  __shared__ int any_nonbool;
  if (threadIdx.x == 0) any_nonbool = 0;
  __syncthreads();
  int bad = 0;
  for (int i = threadIdx.x; i < 4096; i += 256) {
    uint32_t w = mask[i];
    bad |= (w > 1u) ? 1 : 0;
  }
  if (bad) any_nonbool = 1;
  __syncthreads();
  if (threadIdx.x == 0) *flag = any_nonbool;
}

// ---- conversion kernels (grid-stride) ----
__global__ void cvt_x_kernel(const float* __restrict__ x,
                             uint16_t* __restrict__ xh, int n8) {
  const int stride = gridDim.x * blockDim.x;
  for (int i = blockIdx.x * blockDim.x + threadIdx.x; i < n8; i += stride) {
    const float4* src = (const float4*)x + (size_t)i * 2;
    float4 a = src[0], b = src[1];
    u16x8 o;
    o[0] = f32_to_bf16_rne(a.x); o[1] = f32_to_bf16_rne(a.y);
    o[2] = f32_to_bf16_rne(a.z); o[3] = f32_to_bf16_rne(a.w);
    o[4] = f32_to_bf16_rne(b.x); o[5] = f32_to_bf16_rne(b.y);
    o[6] = f32_to_bf16_rne(b.z); o[7] = f32_to_bf16_rne(b.w);
    *((u16x8*)xh + i) = o;
  }
}

__global__ void cvt_w_kernel(const float* __restrict__ w,
                             const void* __restrict__ mask,
                             const int* __restrict__ flag,
                             uint16_t* __restrict__ wh, int n8) {
  const int stride = gridDim.x * blockDim.x;
  const int isU8 = *flag;  // wave-uniform
  for (int i = blockIdx.x * blockDim.x + threadIdx.x; i < n8; i += stride) {
    const float4* src = (const float4*)w + (size_t)i * 2;
    float4 a = src[0], b = src[1];
    float vals[8] = {a.x, a.y, a.z, a.w, b.x, b.y, b.z, b.w};
    int m[8];
    if (isU8) {
      uint64_t mb = *((const uint64_t*)mask + i);
#pragma unroll
      for (int j = 0; j < 8; ++j) m[j] = (int)((mb >> (8 * j)) & 0xffu);
    } else {
      const int4* mp = (const int4*)mask + (size_t)i * 2;
      int4 ma = mp[0], mb4 = mp[1];
      m[0] = ma.x; m[1] = ma.y; m[2] = ma.z; m[3] = ma.w;
      m[4] = mb4.x; m[5] = mb4.y; m[6] = mb4.z; m[7] = mb4.w;
    }
    u16x8 o;
#pragma unroll
    for (int j = 0; j < 8; ++j)
      o[j] = m[j] ? f32_to_bf16_rne(vals[j]) : (uint16_t)0;
    *((u16x8*)wh + i) = o;
  }
}

// ---- 4-phase pipelined 256^2 bf16 MFMA GEMM (32x32x16) ----

#define BARRIER() do { asm volatile("" ::: "memory");            \
                       __builtin_amdgcn_s_barrier();             \
                       asm volatile("" ::: "memory"); } while (0)
#define WAITV(n)  asm volatile("s_waitcnt vmcnt(" #n ")" ::: "memory")

__global__ __launch_bounds__(512, 2) void gemm_bias_256(
    const uint16_t* __restrict__ A, const uint16_t* __restrict__ B,
    const float* __restrict__ bias, float* __restrict__ C) {
  constexpr int NT = KDIM / 64;  // 64 K-tiles of 64, 4 slices of 16 each

  // [2 dbuf][4 slices][A 8KB | B 8KB] = 128 KiB
  __shared__ __align__(16) uint8_t smem[2 * 65536];

  const int bid = blockIdx.x;
  const int cpx = gridDim.x >> 3;            // 512/8=64, bijective
  const int wg  = (bid & 7) * cpx + (bid >> 3);
  const int bm  = wg / 16, bn = wg % 16;     // NBN = 4096/256 = 16

  const int tid  = threadIdx.x;
  const int wave = tid >> 6, lane = tid & 63;
  const int wm = wave >> 2, wn = wave & 3;   // 2x4 wave grid, 128x64 per wave
  const int lr = lane & 31, lh = lane >> 5;  // frag row/col, K-half

  // staging: thread covers (row = tid&255, khalf = tid>>8), 8 bf16 = 16 B.
  // LDS slice layout [khalf][256 rows][8] -> dest = tid*16 (thread-linear).
  const size_t grow = (size_t)(tid & 255) * KDIM + (size_t)(tid >> 8) * 8;
  const uint16_t* Ab = A + (size_t)bm * 256 * KDIM + grow;
  const uint16_t* Bb = B + (size_t)bn * 256 * KDIM + grow;
  const uint32_t sdst = (uint32_t)tid * 16;

  // compute-side: frag read = 16 B at [lh][row'][0], row' = wgrid + mi*32 + lr
  const uint32_t aro = (uint32_t)(lh * 4096 + (wm * 128 + lr) * 16);
  const uint32_t bro = (uint32_t)(8192 + lh * 4096 + (wn * 64 + lr) * 16);

  f32x16 acc[4][2] = {};

#define STAGE_SLICE(kelem, bufb, ph) do {                                      \
    __builtin_amdgcn_global_load_lds(                                          \
        (const __attribute__((address_space(1))) void*)(Ab + (kelem) + (ph) * 16), \
        (__attribute__((address_space(3))) void*)(smem + (bufb) + (ph) * 16384 + sdst), \
        16, 0, 0);                                                             \
    __builtin_amdgcn_global_load_lds(                                          \
        (const __attribute__((address_space(1))) void*)(Bb + (kelem) + (ph) * 16), \
        (__attribute__((address_space(3))) void*)(smem + (bufb) + (ph) * 16384 + 8192 + sdst), \
        16, 0, 0);                                                             \
  } while (0)

#define PHASE_COMPUTE(bufb, ph) do {                                           \
    const uint8_t* sb_ = smem + (bufb) + (ph) * 16384;                         \
    bf16x8 bf0 = *(const bf16x8*)(sb_ + bro);                                  \
    bf16x8 bf1 = *(const bf16x8*)(sb_ + bro + 512);                            \
    bf16x8 af0 = *(const bf16x8*)(sb_ + aro);                                  \
    bf16x8 af1 = *(const bf16x8*)(sb_ + aro + 512);                            \
    bf16x8 af2 = *(const bf16x8*)(sb_ + aro + 1024);                           \
    bf16x8 af3 = *(const bf16x8*)(sb_ + aro + 1536);                           \
    __builtin_amdgcn_s_setprio(1);                                             \
    acc[0][0] = __builtin_amdgcn_mfma_f32_32x32x16_bf16(af0, bf0, acc[0][0], 0, 0, 0); \
    acc[0][1] = __builtin_amdgcn_mfma_f32_32x32x16_bf16(af0, bf1, acc[0][1], 0, 0, 0); \
    acc[1][0] = __builtin_amdgcn_mfma_f32_32x32x16_bf16(af1, bf0, acc[1][0], 0, 0, 0); \
    acc[1][1] = __builtin_amdgcn_mfma_f32_32x32x16_bf16(af1, bf1, acc[1][1], 0, 0, 0); \
    acc[2][0] = __builtin_amdgcn_mfma_f32_32x32x16_bf16(af2, bf0, acc[2][0], 0, 0, 0); \
    acc[2][1] = __builtin_amdgcn_mfma_f32_32x32x16_bf16(af2, bf1, acc[2][1], 0, 0, 0); \
    acc[3][0] = __builtin_amdgcn_mfma_f32_32x32x16_bf16(af3, bf0, acc[3][0], 0, 0, 0); \
    acc[3][1] = __builtin_amdgcn_mfma_f32_32x32x16_bf16(af3, bf1, acc[3][1], 0, 0, 0); \
    __builtin_amdgcn_s_setprio(0);                                             \
  } while (0)

  // prologue: all 4 slices of tile 0 (8 loads, oldest = slice 0)
  STAGE_SLICE(0, 0, 0);
  STAGE_SLICE(0, 0, 1);
  STAGE_SLICE(0, 0, 2);
  STAGE_SLICE(0, 0, 3);

  for (int t = 0; t < NT - 1; ++t) {
    const uint32_t bp = (uint32_t)(t & 1) * 65536u;
    const uint32_t bq = bp ^ 65536u;
    const int kn = (t + 1) * 64;
    // phase ph: wait slice ph landed (6 newer loads in flight), stage slice
    // ph of tile t+1, compute k-step ph of tile t.
    WAITV(6); BARRIER(); STAGE_SLICE(kn, bq, 0); PHASE_COMPUTE(bp, 0);
    WAITV(6); BARRIER(); STAGE_SLICE(kn, bq, 1); PHASE_COMPUTE(bp, 1);
    WAITV(6); BARRIER(); STAGE_SLICE(kn, bq, 2); PHASE_COMPUTE(bp, 2);
    WAITV(6); BARRIER(); STAGE_SLICE(kn, bq, 3); PHASE_COMPUTE(bp, 3);
  }
  {  // tail tile NT-1 (odd -> buf 1): no staging, drain 6,4,2,0
    const uint32_t bp = (uint32_t)((NT - 1) & 1) * 65536u;
    WAITV(6); BARRIER(); PHASE_COMPUTE(bp, 0);
    WAITV(4); BARRIER(); PHASE_COMPUTE(bp, 1);
    WAITV(2); BARRIER(); PHASE_COMPUTE(bp, 2);
    WAITV(0); BARRIER(); PHASE_COMPUTE(bp, 3);
  }

  // epilogue: 32x32 C/D layout col = lane&31, row = (r&3) + 8*(r>>2) + 4*lh
  const int rowg = bm * 256 + wm * 128;
  const int colg = bn * 256 + wn * 64 + lr;
#pragma unroll
  for (int ni = 0; ni < 2; ++ni) {
    const int col = colg + ni * 32;
    const float bv = bias[col];
#pragma unroll
    for (int mi = 0; mi < 4; ++mi) {
#pragma unroll
      for (int r = 0; r < 16; ++r) {
        const int row = rowg + mi * 32 + (r & 3) + 8 * (r >> 2) + 4 * lh;
        C[(size_t)row * NDIM + col] = acc[mi][ni][r] + bv;
      }
    }
  }
#undef STAGE_SLICE
#undef PHASE_COMPUTE
}

extern "C" void kernel_launch(void* const* d_in, const int* in_sizes, int n_in,
                              void* d_out, int out_size, void* d_ws, size_t ws_size,
                              hipStream_t stream) {
  const float* x    = (const float*)d_in[0];
  const float* w    = (const float*)d_in[1];
  const void*  mk   = (const void*)d_in[2];
  const float* bias = (const float*)d_in[3];
  float* out        = (float*)d_out;

  const size_t need = (size_t)MDIM * KDIM * 2 + (size_t)NDIM * KDIM * 2;
  if (ws_size < need) return;

  uint16_t* xh = (uint16_t*)d_ws;
  uint16_t* wh = xh + (size_t)MDIM * KDIM;

  int* flag = (int*)d_out;  // overwritten by GEMM epilogue
  detect_mask_kernel<<<1, 256, 0, stream>>>((const uint32_t*)mk, flag);

  const int nx8 = MDIM * KDIM / 8;
  const int nw8 = NDIM * KDIM / 8;
  cvt_x_kernel<<<2048, 256, 0, stream>>>(x, xh, nx8);
  cvt_w_kernel<<<2048, 256, 0, stream>>>(w, mk, flag, wh, nw8);

  const int grid = (MDIM / 256) * (NDIM / 256);  // 512
  gemm_bias_256<<<grid, 512, 0, stream>>>(xh, wh, bias, out);
}